// Round 1
// baseline (5796.582 us; speedup 1.0000x reference)
//
#include <hip/hip_runtime.h>
#include <math.h>

// Problem constants (from reference)
namespace {
constexpr int kNB  = 16;
constexpr int kNA  = 1024;
constexpr int kP   = 65536;          // NA * NEI pairs per batch (power of 2)
constexpr int kNW  = 8;              // NWAVE
constexpr int kLI  = 13;             // LEN_IDX = 1 + 3 + 9
constexpr int kTot = kNB * kNA;      // 16384 atoms
constexpr int kAccStride = kLI * kNW; // 104 floats per atom
constexpr float kInvCut = 1.0f / 6.0f;
constexpr float kPi = 3.14159265358979323846f;
}

// Scatter kernel: one thread per pair. Computes f_cut, unit vector, radial[8],
// angular[13]; atomically accumulates the 13x8 outer product into acc[center].
__global__ __launch_bounds__(256) void pair_scatter(
    const float* __restrict__ coords,   // [NB*NA*3]
    const int*   __restrict__ aidx,     // [NB*2*P]
    const float* __restrict__ shifts,   // [NB*P*3]
    const int*   __restrict__ species,  // [NB*NA]
    const float* __restrict__ rs,       // [NTYPE*NWAVE]
    const float* __restrict__ inta,     // [NTYPE*NWAVE]
    float* __restrict__ acc)            // [Tot*104]
{
  const int t = blockIdx.x * blockDim.x + threadIdx.x;   // 0 .. NB*P-1
  const int b = t >> 16;            // t / kP
  const int p = t & (kP - 1);       // t % kP

  const int i0 = aidx[(b * 2 + 0) * kP + p];   // center atom (within batch)
  const int i1 = aidx[(b * 2 + 1) * kP + p];   // neighbor atom
  const int gi = b * kNA + i0;
  const int gj = b * kNA + i1;

  const size_t sbase = (size_t)(b * kP + p) * 3;
  const float sx = shifts[sbase + 0];
  const float sy = shifts[sbase + 1];
  const float sz = shifts[sbase + 2];
  const bool valid = (sx > -1.0e9f) & (sy > -1.0e9f) & (sz > -1.0e9f);

  const float dx = coords[gi * 3 + 0] - coords[gj * 3 + 0] + sx;
  const float dy = coords[gi * 3 + 1] - coords[gj * 3 + 1] + sy;
  const float dz = coords[gi * 3 + 2] - coords[gj * 3 + 2] + sz;

  const float d2 = dx * dx + dy * dy + dz * dz;
  const float dist = sqrtf(d2);
  const float dist_safe = (dist > 1e-12f) ? dist : 1.0f;
  const float inv = 1.0f / dist_safe;

  float r = dist * kInvCut;
  r = fminf(r, 1.0f);
  float f = 0.5f * (__cosf(kPi * r) + 1.0f);
  if (!valid) f = 0.0f;
  if (r >= 1.0f) f = 0.0f;   // exact zero past cutoff (cos(pi) rounding safety)

  if (f == 0.0f) return;     // contribution is exactly zero for all 104 terms

  const float ux = dx * inv, uy = dy * inv, uz = dz * inv;
  const int s = species[gi];

  float rad[kNW];
#pragma unroll
  for (int w = 0; w < kNW; ++w) {
    const float dr = dist - rs[s * kNW + w];
    rad[w] = __expf(-inta[s * kNW + w] * dr * dr);
  }

  float ang[kLI];
  ang[0] = f;
  ang[1] = f * ux; ang[2] = f * uy; ang[3] = f * uz;
  ang[4]  = ang[1] * ux; ang[5]  = ang[1] * uy; ang[6]  = ang[1] * uz;
  ang[7]  = ang[2] * ux; ang[8]  = ang[2] * uy; ang[9]  = ang[2] * uz;
  ang[10] = ang[3] * ux; ang[11] = ang[3] * uy; ang[12] = ang[3] * uz;

  float* base = acc + (size_t)gi * kAccStride;
#pragma unroll
  for (int k = 0; k < kLI; ++k) {
#pragma unroll
    for (int w = 0; w < kNW; ++w) {
      atomicAdd(base + k * kNW + w, ang[k] * rad[w]);
    }
  }
}

// Epilogue: one thread per (atom, wave). Grouped sums of squares -> out.
// out[i, l*8 + w], groups l: {k=0}, {k=1..3}, {k=4..12}, scaled by params[s].
__global__ __launch_bounds__(256) void density_out(
    const float* __restrict__ acc,      // [Tot*104]
    const int*   __restrict__ species,  // [Tot]
    const float* __restrict__ params,   // [NTYPE]
    float* __restrict__ out)            // [Tot*24]
{
  const int t = blockIdx.x * blockDim.x + threadIdx.x;  // 0 .. Tot*8-1
  const int i = t >> 3;
  const int w = t & 7;
  const int s = species[i];
  const float pm = params[s];
  const float* a = acc + (size_t)i * kAccStride + w;

  float v = a[0 * kNW];
  const float o0 = v * v;

  float o1 = 0.0f;
#pragma unroll
  for (int k = 1; k < 4; ++k) { v = a[k * kNW]; o1 += v * v; }

  float o2 = 0.0f;
#pragma unroll
  for (int k = 4; k < 13; ++k) { v = a[k * kNW]; o2 += v * v; }

  float* o = out + (size_t)i * 24;
  o[0 * kNW + w] = pm * o0;
  o[1 * kNW + w] = pm * o1;
  o[2 * kNW + w] = pm * o2;
}

extern "C" void kernel_launch(void* const* d_in, const int* in_sizes, int n_in,
                              void* d_out, int out_size, void* d_ws, size_t ws_size,
                              hipStream_t stream) {
  const float* coords  = (const float*)d_in[0];  // (16,1024,3)
  // d_in[1] = numatoms (unused)
  const int*   aidx    = (const int*)d_in[2];    // (16,2,65536)
  const float* shifts  = (const float*)d_in[3];  // (16,65536,3)
  const int*   species = (const int*)d_in[4];    // (16384,)
  const float* rs      = (const float*)d_in[5];  // (4,8)
  const float* inta    = (const float*)d_in[6];  // (4,8)
  const float* params  = (const float*)d_in[7];  // (4,)
  float* out = (float*)d_out;                    // (16384, 24)

  float* acc = (float*)d_ws;                     // 16384*104 floats = 6.8 MB
  const size_t acc_bytes = (size_t)kTot * kAccStride * sizeof(float);
  hipMemsetAsync(acc, 0, acc_bytes, stream);

  const int npairs = kNB * kP;                   // 1,048,576
  pair_scatter<<<npairs / 256, 256, 0, stream>>>(coords, aidx, shifts, species,
                                                 rs, inta, acc);
  density_out<<<(kTot * kNW) / 256, 256, 0, stream>>>(acc, species, params, out);
}

// Round 2
// 181.988 us; speedup vs baseline: 31.8515x; 31.8515x over previous
//
#include <hip/hip_runtime.h>
#include <math.h>

namespace {
constexpr int kNB  = 16;
constexpr int kNA  = 1024;
constexpr int kP   = 65536;           // pairs per batch (power of 2)
constexpr int kNW  = 8;               // NWAVE
constexpr int kTot = kNB * kNA;       // 16384 atoms
constexpr int kMaxNei = 128;          // bucket capacity (mean 64, std 8 -> 8 sigma)
constexpr float kInvCut = 1.0f / 6.0f;
constexpr float kPi = 3.14159265358979323846f;
}

// Phase A: one thread per pair. Compute (dx,dy,dz,f_cut); append to the
// center atom's bucket. Pairs with f_cut == 0 contribute nothing -> dropped.
__global__ __launch_bounds__(256) void build_lists(
    const float* __restrict__ coords,   // [Tot*3]
    const int*   __restrict__ aidx,     // [NB*2*P]
    const float* __restrict__ shifts,   // [NB*P*3]
    int*    __restrict__ cnt,           // [Tot]
    float4* __restrict__ lists)         // [Tot*kMaxNei]
{
  const int t = blockIdx.x * blockDim.x + threadIdx.x;   // 0 .. NB*P-1
  const int b = t >> 16;
  const int p = t & (kP - 1);

  const int i0 = aidx[(b * 2 + 0) * kP + p];   // center
  const int i1 = aidx[(b * 2 + 1) * kP + p];   // neighbor
  const int gi = b * kNA + i0;
  const int gj = b * kNA + i1;

  const size_t sb = (size_t)(b * kP + p) * 3;
  const float sx = shifts[sb + 0];
  const float sy = shifts[sb + 1];
  const float sz = shifts[sb + 2];
  const bool valid = (sx > -1.0e9f) & (sy > -1.0e9f) & (sz > -1.0e9f);

  const float dx = coords[gi * 3 + 0] - coords[gj * 3 + 0] + sx;
  const float dy = coords[gi * 3 + 1] - coords[gj * 3 + 1] + sy;
  const float dz = coords[gi * 3 + 2] - coords[gj * 3 + 2] + sz;

  const float d2 = dx * dx + dy * dy + dz * dz;
  const float dist = sqrtf(d2);
  const float r = dist * kInvCut;
  float f = 0.5f * (__cosf(kPi * fminf(r, 1.0f)) + 1.0f);
  if (!valid | (r >= 1.0f)) f = 0.0f;
  if (f == 0.0f) return;               // exactly-zero contribution

  const int pos = atomicAdd(&cnt[gi], 1);
  if (pos < kMaxNei) {
    lists[(size_t)gi * kMaxNei + pos] = make_float4(dx, dy, dz, f);
  }
}

// Phase B: one thread per (atom, w). Owns acc[13] for its wave channel in
// registers; loops the atom's bucket; fused epilogue (grouped sum-of-squares
// times params[species]). No atomics.
__global__ __launch_bounds__(256) void gather_density(
    const float4* __restrict__ lists,   // [Tot*kMaxNei]
    const int*    __restrict__ cnt,     // [Tot]
    const int*    __restrict__ species, // [Tot]
    const float*  __restrict__ rs,      // [NTYPE*NWAVE]
    const float*  __restrict__ inta,    // [NTYPE*NWAVE]
    const float*  __restrict__ params,  // [NTYPE]
    float* __restrict__ out)            // [Tot*24]
{
  const int t = blockIdx.x * blockDim.x + threadIdx.x;  // 0 .. Tot*8-1
  const int i = t >> 3;
  const int w = t & 7;
  const int s = species[i];
  const float rsw   = rs[s * kNW + w];
  const float intaw = inta[s * kNW + w];
  const int n = min(cnt[i], kMaxNei);
  const float4* __restrict__ L = lists + (size_t)i * kMaxNei;

  float a0 = 0.f, a1 = 0.f, a2 = 0.f, a3 = 0.f, a4 = 0.f, a5 = 0.f, a6 = 0.f;
  float a7 = 0.f, a8 = 0.f, a9 = 0.f, a10 = 0.f, a11 = 0.f, a12 = 0.f;

  for (int j = 0; j < n; ++j) {
    const float4 q = L[j];
    const float d2 = q.x * q.x + q.y * q.y + q.z * q.z;
    const float dist = sqrtf(d2);
    const float inv = (dist > 1e-12f) ? (1.0f / dist) : 1.0f;
    const float ux = q.x * inv, uy = q.y * inv, uz = q.z * inv;
    const float dr = dist - rsw;
    const float rad = __expf(-intaw * dr * dr);
    const float fr = q.w * rad;
    a0 += fr;
    const float rx = fr * ux, ry = fr * uy, rz = fr * uz;
    a1 += rx;       a2 += ry;       a3 += rz;
    a4 += rx * ux;  a5 += rx * uy;  a6 += rx * uz;
    a7 += ry * ux;  a8 += ry * uy;  a9 += ry * uz;
    a10 += rz * ux; a11 += rz * uy; a12 += rz * uz;
  }

  const float pm = params[s];
  const float o0 = a0 * a0;
  const float o1 = a1 * a1 + a2 * a2 + a3 * a3;
  const float o2 = a4 * a4 + a5 * a5 + a6 * a6 + a7 * a7 + a8 * a8 +
                   a9 * a9 + a10 * a10 + a11 * a11 + a12 * a12;

  float* o = out + (size_t)i * 24;
  o[0 * kNW + w] = pm * o0;
  o[1 * kNW + w] = pm * o1;
  o[2 * kNW + w] = pm * o2;
}

extern "C" void kernel_launch(void* const* d_in, const int* in_sizes, int n_in,
                              void* d_out, int out_size, void* d_ws, size_t ws_size,
                              hipStream_t stream) {
  const float* coords  = (const float*)d_in[0];  // (16,1024,3)
  const int*   aidx    = (const int*)d_in[2];    // (16,2,65536)
  const float* shifts  = (const float*)d_in[3];  // (16,65536,3)
  const int*   species = (const int*)d_in[4];    // (16384,)
  const float* rs      = (const float*)d_in[5];  // (4,8)
  const float* inta    = (const float*)d_in[6];  // (4,8)
  const float* params  = (const float*)d_in[7];  // (4,)
  float* out = (float*)d_out;                    // (16384, 24)

  // Workspace layout: [cnt: 16384 int][lists: 16384*128 float4]
  int*    cnt   = (int*)d_ws;
  float4* lists = (float4*)((char*)d_ws + (size_t)kTot * sizeof(int));

  hipMemsetAsync(cnt, 0, (size_t)kTot * sizeof(int), stream);

  const int npairs = kNB * kP;                   // 1,048,576
  build_lists<<<npairs / 256, 256, 0, stream>>>(coords, aidx, shifts, cnt, lists);
  gather_density<<<(kTot * kNW) / 256, 256, 0, stream>>>(lists, cnt, species,
                                                         rs, inta, params, out);
}

// Round 3
// 156.453 us; speedup vs baseline: 37.0499x; 1.1632x over previous
//
#include <hip/hip_runtime.h>
#include <hip/hip_fp16.h>
#include <math.h>

namespace {
constexpr int kNB  = 16;
constexpr int kNA  = 1024;
constexpr int kP   = 65536;           // pairs per batch (power of 2)
constexpr int kNW  = 8;               // NWAVE
constexpr int kTot = kNB * kNA;       // 16384 atoms
constexpr int kMaxNei = 128;          // bucket capacity (mean 64, sigma 8)
constexpr float kInvCut = 1.0f / 6.0f;
constexpr float kPi = 3.14159265358979323846f;
}

// Phase A: one thread per pair. Compute (dx,dy,dz,f_cut), pack to f16x4 (8B),
// append to center atom's bucket. XCD-swizzled so each XCD (blockIdx%8 round
// robin) owns exactly 2 batches -> scatter region 2MB fits its 4MB L2, and
// partial-line writes coalesce in L2 before eviction.
__global__ __launch_bounds__(256) void build_lists(
    const float* __restrict__ coords,   // [Tot*3]
    const int*   __restrict__ aidx,     // [NB*2*P]
    const float* __restrict__ shifts,   // [NB*P*3]
    int*   __restrict__ cnt,            // [Tot]
    uint2* __restrict__ lists)          // [Tot*kMaxNei], f16x4 payloads
{
  // blockIdx: 4096 blocks. r = XCD slot, q>>8 selects batch r or r+8.
  const int r = blockIdx.x & 7;
  const int q = blockIdx.x >> 3;                 // 0..511
  const int b = r + ((q >> 8) << 3);             // batch: r or r+8
  const int p = ((q & 255) << 8) | threadIdx.x;  // 0..65535

  const int i0 = aidx[(b * 2 + 0) * kP + p];     // center
  const int i1 = aidx[(b * 2 + 1) * kP + p];     // neighbor
  const int gi = b * kNA + i0;
  const int gj = b * kNA + i1;

  const size_t sb = (size_t)(b * kP + p) * 3;
  const float sx = shifts[sb + 0];
  const float sy = shifts[sb + 1];
  const float sz = shifts[sb + 2];
  const bool valid = (sx > -1.0e9f) & (sy > -1.0e9f) & (sz > -1.0e9f);

  const float dx = coords[gi * 3 + 0] - coords[gj * 3 + 0] + sx;
  const float dy = coords[gi * 3 + 1] - coords[gj * 3 + 1] + sy;
  const float dz = coords[gi * 3 + 2] - coords[gj * 3 + 2] + sz;

  const float dist = sqrtf(dx * dx + dy * dy + dz * dz);
  const float rr = dist * kInvCut;
  float f = 0.5f * (__cosf(kPi * fminf(rr, 1.0f)) + 1.0f);
  if (!valid | (rr >= 1.0f)) f = 0.0f;
  if (f == 0.0f) return;               // exactly-zero contribution

  const int pos = atomicAdd(&cnt[gi], 1);
  if (pos < kMaxNei) {
    const __half2 h0 = __floats2half2_rn(dx, dy);
    const __half2 h1 = __floats2half2_rn(dz, f);
    uint2 u;
    u.x = __builtin_bit_cast(unsigned, h0);
    u.y = __builtin_bit_cast(unsigned, h1);
    lists[(size_t)gi * kMaxNei + pos] = u;
  }
}

// Phase B: 32 threads per atom: k = pair-slice (0..3), w = wave channel (0..7).
// Each thread accumulates 13 angular sums for its (k,w) over pairs j=k,k+4,...
// then reduces over k with shfl_xor(8),shfl_xor(16) (within the 32-lane atom
// group), and lane k==0 writes the fused epilogue.
__global__ __launch_bounds__(256) void gather_density(
    const uint2* __restrict__ lists,    // [Tot*kMaxNei]
    const int*   __restrict__ cnt,      // [Tot]
    const int*   __restrict__ species,  // [Tot]
    const float* __restrict__ rs,       // [NTYPE*NWAVE]
    const float* __restrict__ inta,     // [NTYPE*NWAVE]
    const float* __restrict__ params,   // [NTYPE]
    float* __restrict__ out)            // [Tot*24]
{
  const int t = blockIdx.x * blockDim.x + threadIdx.x;  // 0 .. Tot*32-1
  const int i = t >> 5;          // atom
  const int k = (t >> 3) & 3;    // pair slice
  const int w = t & 7;           // wave channel
  const int s = species[i];
  const float rsw   = rs[s * kNW + w];
  const float intaw = inta[s * kNW + w];
  const int n = min(cnt[i], kMaxNei);
  const uint2* __restrict__ L = lists + (size_t)i * kMaxNei;

  float a[13];
#pragma unroll
  for (int m = 0; m < 13; ++m) a[m] = 0.0f;

  for (int j = k; j < n; j += 4) {
    const uint2 u = L[j];
    const float2 f0 = __half22float2(__builtin_bit_cast(__half2, u.x));
    const float2 f1 = __half22float2(__builtin_bit_cast(__half2, u.y));
    const float dxv = f0.x, dyv = f0.y, dzv = f1.x, f = f1.y;
    const float d2 = dxv * dxv + dyv * dyv + dzv * dzv;
    const float dist = sqrtf(d2);
    const float inv = (dist > 1e-12f) ? (1.0f / dist) : 1.0f;
    const float ux = dxv * inv, uy = dyv * inv, uz = dzv * inv;
    const float dr = dist - rsw;
    const float rad = __expf(-intaw * dr * dr);
    const float fr = f * rad;
    a[0] += fr;
    const float rx = fr * ux, ry = fr * uy, rz = fr * uz;
    a[1] += rx;        a[2] += ry;        a[3] += rz;
    a[4] += rx * ux;   a[5] += rx * uy;   a[6] += rx * uz;
    a[7] += ry * ux;   a[8] += ry * uy;   a[9] += ry * uz;
    a[10] += rz * ux;  a[11] += rz * uy;  a[12] += rz * uz;
  }

  // Reduce the 13 accumulators across the 4 k-slices (lanes differing in
  // bits 3..4 of the wave lane id; atom group = 32 lanes, so both stay inside).
#pragma unroll
  for (int m = 0; m < 13; ++m) {
    a[m] += __shfl_xor(a[m], 8);
    a[m] += __shfl_xor(a[m], 16);
  }

  if (k == 0) {
    const float pm = params[s];
    const float o0 = a[0] * a[0];
    const float o1 = a[1] * a[1] + a[2] * a[2] + a[3] * a[3];
    const float o2 = a[4] * a[4] + a[5] * a[5] + a[6] * a[6] +
                     a[7] * a[7] + a[8] * a[8] + a[9] * a[9] +
                     a[10] * a[10] + a[11] * a[11] + a[12] * a[12];
    float* o = out + (size_t)i * 24;
    o[0 * kNW + w] = pm * o0;
    o[1 * kNW + w] = pm * o1;
    o[2 * kNW + w] = pm * o2;
  }
}

extern "C" void kernel_launch(void* const* d_in, const int* in_sizes, int n_in,
                              void* d_out, int out_size, void* d_ws, size_t ws_size,
                              hipStream_t stream) {
  const float* coords  = (const float*)d_in[0];  // (16,1024,3)
  const int*   aidx    = (const int*)d_in[2];    // (16,2,65536)
  const float* shifts  = (const float*)d_in[3];  // (16,65536,3)
  const int*   species = (const int*)d_in[4];    // (16384,)
  const float* rs      = (const float*)d_in[5];  // (4,8)
  const float* inta    = (const float*)d_in[6];  // (4,8)
  const float* params  = (const float*)d_in[7];  // (4,)
  float* out = (float*)d_out;                    // (16384, 24)

  // Workspace: [cnt: 16384 int][lists: 16384*128 uint2 = 16 MB]
  int*   cnt   = (int*)d_ws;
  uint2* lists = (uint2*)((char*)d_ws + (size_t)kTot * sizeof(int));

  hipMemsetAsync(cnt, 0, (size_t)kTot * sizeof(int), stream);

  const int npairs = kNB * kP;                   // 1,048,576
  build_lists<<<npairs / 256, 256, 0, stream>>>(coords, aidx, shifts, cnt, lists);
  gather_density<<<(kTot * 32) / 256, 256, 0, stream>>>(lists, cnt, species,
                                                        rs, inta, params, out);
}

// Round 4
// 154.746 us; speedup vs baseline: 37.4587x; 1.0110x over previous
//
#include <hip/hip_runtime.h>
#include <hip/hip_fp16.h>
#include <math.h>

namespace {
constexpr int kNB  = 16;
constexpr int kNA  = 1024;
constexpr int kP   = 65536;           // pairs per batch (power of 2)
constexpr int kNW  = 8;               // NWAVE
constexpr int kTot = kNB * kNA;       // 16384 atoms
constexpr int kMaxNei = 128;          // bucket capacity (mean 64, sigma 8)
constexpr float kInvCut = 1.0f / 6.0f;
constexpr float kPi = 3.14159265358979323846f;
}

// Phase A: one thread per pair. Streaming inputs use non-temporal loads so
// the XCD L2 keeps the scattered bucket lines resident (write-merging into
// full lines). XCD-swizzled: batch b handled by XCD b%8 (round-robin blocks).
__global__ __launch_bounds__(256) void build_lists(
    const float* __restrict__ coords,   // [Tot*3]
    const int*   __restrict__ aidx,     // [NB*2*P]
    const float* __restrict__ shifts,   // [NB*P*3]
    int*   __restrict__ cnt,            // [Tot]
    uint2* __restrict__ lists)          // [Tot*kMaxNei], f16x4 payloads
{
  const int r = blockIdx.x & 7;                  // XCD slot
  const int q = blockIdx.x >> 3;                 // 0..511
  const int b = r + ((q >> 8) << 3);             // batch: r or r+8
  const int p = ((q & 255) << 8) | threadIdx.x;  // 0..65535

  const int i0 = __builtin_nontemporal_load(&aidx[(b * 2 + 0) * kP + p]);
  const int i1 = __builtin_nontemporal_load(&aidx[(b * 2 + 1) * kP + p]);
  const int gi = b * kNA + i0;
  const int gj = b * kNA + i1;

  const size_t sb = (size_t)(b * kP + p) * 3;
  const float sx = __builtin_nontemporal_load(&shifts[sb + 0]);
  const float sy = __builtin_nontemporal_load(&shifts[sb + 1]);
  const float sz = __builtin_nontemporal_load(&shifts[sb + 2]);
  const bool valid = (sx > -1.0e9f) & (sy > -1.0e9f) & (sz > -1.0e9f);

  const float dx = coords[gi * 3 + 0] - coords[gj * 3 + 0] + sx;
  const float dy = coords[gi * 3 + 1] - coords[gj * 3 + 1] + sy;
  const float dz = coords[gi * 3 + 2] - coords[gj * 3 + 2] + sz;

  const float dist = sqrtf(dx * dx + dy * dy + dz * dz);
  const float rr = dist * kInvCut;
  float f = 0.5f * (__cosf(kPi * fminf(rr, 1.0f)) + 1.0f);
  if (!valid | (rr >= 1.0f)) f = 0.0f;
  if (f == 0.0f) return;               // exactly-zero contribution

  const int pos = atomicAdd(&cnt[gi], 1);
  if (pos < kMaxNei) {
    const __half2 h0 = __floats2half2_rn(dx, dy);
    const __half2 h1 = __floats2half2_rn(dz, f);
    uint2 u;
    u.x = __builtin_bit_cast(unsigned, h0);
    u.y = __builtin_bit_cast(unsigned, h1);
    lists[(size_t)gi * kMaxNei + pos] = u;       // normal store: merge in L2
  }
}

// Phase B: 32 threads per atom (k = pair slice 0..3, w = wave channel 0..7).
// Block->batch mapping mirrors build_lists' XCD swizzle so bucket reads hit
// the same XCD's L2 that holds the dirty lines.
__global__ __launch_bounds__(256) void gather_density(
    const uint2* __restrict__ lists,    // [Tot*kMaxNei]
    const int*   __restrict__ cnt,      // [Tot]
    const int*   __restrict__ species,  // [Tot]
    const float* __restrict__ rs,       // [NTYPE*NWAVE]
    const float* __restrict__ inta,     // [NTYPE*NWAVE]
    const float* __restrict__ params,   // [NTYPE]
    float* __restrict__ out)            // [Tot*24]
{
  // 2048 blocks, 8 atoms per block. r = XCD slot; batch b has b%8 == r.
  const int r = blockIdx.x & 7;
  const int m = blockIdx.x >> 3;                 // 0..255
  const int b = r + ((m >> 7) << 3);             // batch: r or r+8
  const int g = m & 127;                         // atom octet within batch
  const int i = b * kNA + g * 8 + (threadIdx.x >> 5);
  const int k = (threadIdx.x >> 3) & 3;          // pair slice
  const int w = threadIdx.x & 7;                 // wave channel

  const int s = species[i];
  const float rsw   = rs[s * kNW + w];
  const float intaw = inta[s * kNW + w];
  const int n = min(cnt[i], kMaxNei);
  const uint2* __restrict__ L = lists + (size_t)i * kMaxNei;

  float a[13];
#pragma unroll
  for (int mm = 0; mm < 13; ++mm) a[mm] = 0.0f;

#pragma unroll 4
  for (int j = k; j < n; j += 4) {
    const uint2 u = L[j];
    const float2 f0 = __half22float2(__builtin_bit_cast(__half2, u.x));
    const float2 f1 = __half22float2(__builtin_bit_cast(__half2, u.y));
    const float dxv = f0.x, dyv = f0.y, dzv = f1.x, f = f1.y;
    const float d2 = dxv * dxv + dyv * dyv + dzv * dzv;
    const float dist = sqrtf(d2);
    const float inv = (dist > 1e-12f) ? (1.0f / dist) : 1.0f;
    const float ux = dxv * inv, uy = dyv * inv, uz = dzv * inv;
    const float dr = dist - rsw;
    const float rad = __expf(-intaw * dr * dr);
    const float fr = f * rad;
    a[0] += fr;
    const float rx = fr * ux, ry = fr * uy, rz = fr * uz;
    a[1] += rx;        a[2] += ry;        a[3] += rz;
    a[4] += rx * ux;   a[5] += rx * uy;   a[6] += rx * uz;
    a[7] += ry * ux;   a[8] += ry * uy;   a[9] += ry * uz;
    a[10] += rz * ux;  a[11] += rz * uy;  a[12] += rz * uz;
  }

  // Reduce across the 4 k-slices (lanes differing in bits 3..4).
#pragma unroll
  for (int mm = 0; mm < 13; ++mm) {
    a[mm] += __shfl_xor(a[mm], 8);
    a[mm] += __shfl_xor(a[mm], 16);
  }

  if (k == 0) {
    const float pm = params[s];
    const float o0 = a[0] * a[0];
    const float o1 = a[1] * a[1] + a[2] * a[2] + a[3] * a[3];
    const float o2 = a[4] * a[4] + a[5] * a[5] + a[6] * a[6] +
                     a[7] * a[7] + a[8] * a[8] + a[9] * a[9] +
                     a[10] * a[10] + a[11] * a[11] + a[12] * a[12];
    float* o = out + (size_t)i * 24;
    o[0 * kNW + w] = pm * o0;
    o[1 * kNW + w] = pm * o1;
    o[2 * kNW + w] = pm * o2;
  }
}

extern "C" void kernel_launch(void* const* d_in, const int* in_sizes, int n_in,
                              void* d_out, int out_size, void* d_ws, size_t ws_size,
                              hipStream_t stream) {
  const float* coords  = (const float*)d_in[0];  // (16,1024,3)
  const int*   aidx    = (const int*)d_in[2];    // (16,2,65536)
  const float* shifts  = (const float*)d_in[3];  // (16,65536,3)
  const int*   species = (const int*)d_in[4];    // (16384,)
  const float* rs      = (const float*)d_in[5];  // (4,8)
  const float* inta    = (const float*)d_in[6];  // (4,8)
  const float* params  = (const float*)d_in[7];  // (4,)
  float* out = (float*)d_out;                    // (16384, 24)

  // Workspace: [cnt: 16384 int][lists: 16384*128 uint2 = 16 MB]
  int*   cnt   = (int*)d_ws;
  uint2* lists = (uint2*)((char*)d_ws + (size_t)kTot * sizeof(int));

  hipMemsetAsync(cnt, 0, (size_t)kTot * sizeof(int), stream);

  const int npairs = kNB * kP;                   // 1,048,576
  build_lists<<<npairs / 256, 256, 0, stream>>>(coords, aidx, shifts, cnt, lists);
  gather_density<<<(kTot * 32) / 256, 256, 0, stream>>>(lists, cnt, species,
                                                        rs, inta, params, out);
}